// Round 1
// baseline (397.239 us; speedup 1.0000x reference)
//
#include <hip/hip_runtime.h>
#include <cmath>

namespace {
constexpr int H = 256, W = 256, C = 64;
constexpr int HWp = H * W;
}

// K0: transpose w1 [co=64][ci=64][3][3] -> w1t [ci*9+k][co]
__global__ void k_wt(const float* __restrict__ w1, float* __restrict__ w1t) {
    int i = blockIdx.x * 256 + threadIdx.x;
    if (i >= 64 * 576) return;
    int co = i / 576, r = i - co * 576;   // r = ci*9 + k
    w1t[r * 64 + co] = w1[i];
}

// K1: conv1 (3x3, 64->64, zero pad) + SiLU. One thread = one pixel, all 64 co.
__global__ __launch_bounds__(256) void k_conv1(
        const float* __restrict__ x, const float* __restrict__ w1t,
        const float* __restrict__ b1, float* __restrict__ act) {
    const int tx = threadIdx.x & 31, ty = threadIdx.x >> 5;
    const int px = blockIdx.x * 32 + tx;
    const int py = blockIdx.y * 8 + ty;
    const int b  = blockIdx.z;

    float acc[64];
#pragma unroll
    for (int co = 0; co < 64; ++co) acc[co] = b1[co];

    const float* xb = x + (size_t)b * C * HWp + py * W + px;
    int off[9];
    bool val[9];
#pragma unroll
    for (int dy = -1; dy <= 1; ++dy)
#pragma unroll
        for (int dx = -1; dx <= 1; ++dx) {
            int k = (dy + 1) * 3 + (dx + 1);
            off[k] = dy * W + dx;
            val[k] = ((unsigned)(py + dy) < (unsigned)H) &&
                     ((unsigned)(px + dx) < (unsigned)W);
        }

    for (int ci = 0; ci < C; ++ci) {
        float in[9];
#pragma unroll
        for (int k = 0; k < 9; ++k)
            in[k] = val[k] ? xb[ci * HWp + off[k]] : 0.f;
        const float* wp = w1t + ci * 9 * 64;  // uniform -> s_load
#pragma unroll
        for (int k = 0; k < 9; ++k) {
#pragma unroll
            for (int co = 0; co < 64; ++co)
                acc[co] = fmaf(in[k], wp[k * 64 + co], acc[co]);
        }
    }

    float* ap = act + (size_t)b * 64 * HWp + py * W + px;
#pragma unroll
    for (int co = 0; co < 64; ++co) {
        float v = acc[co];
        ap[co * HWp] = v / (1.f + __expf(-v));  // silu
    }
}

// K2: conv2 (3x3, 64->1, zero pad), * dt -> psi [B][H][W]
__global__ __launch_bounds__(256) void k_conv2(
        const float* __restrict__ act, const float* __restrict__ w2,
        const float* __restrict__ b2, const float* __restrict__ dtp,
        float* __restrict__ psi) {
    const int tx = threadIdx.x & 31, ty = threadIdx.x >> 5;
    const int px = blockIdx.x * 32 + tx;
    const int py = blockIdx.y * 8 + ty;
    const int b  = blockIdx.z;

    int off[9];
    bool val[9];
#pragma unroll
    for (int dy = -1; dy <= 1; ++dy)
#pragma unroll
        for (int dx = -1; dx <= 1; ++dx) {
            int k = (dy + 1) * 3 + (dx + 1);
            off[k] = dy * W + dx;
            val[k] = ((unsigned)(py + dy) < (unsigned)H) &&
                     ((unsigned)(px + dx) < (unsigned)W);
        }

    float acc = b2[0];
    const float* ab = act + (size_t)b * 64 * HWp + py * W + px;
    for (int ci = 0; ci < 64; ++ci) {
#pragma unroll
        for (int k = 0; k < 9; ++k) {
            float v = val[k] ? ab[ci * HWp + off[k]] : 0.f;
            acc = fmaf(v, w2[ci * 9 + k], acc);  // w2 uniform -> s_load
        }
    }
    psi[b * HWp + py * W + px] = acc * dtp[0];
}

// K3: curl(psi) -> flow -> bilinear border-clamped sample of 128 channels.
__global__ __launch_bounds__(256) void k_sample(
        const float* __restrict__ zr, const float* __restrict__ zi,
        const float* __restrict__ psi, float* __restrict__ out) {
    const int tx = threadIdx.x & 31, ty = threadIdx.x >> 5;
    const int px = blockIdx.x * 32 + tx;
    const int py = blockIdx.y * 8 + ty;
    const int b  = blockIdx.z;

    const float* pb = psi + b * HWp;
    const int yp = min(py + 1, H - 1), ym = max(py - 1, 0);
    const int xp = min(px + 1, W - 1), xm = max(px - 1, 0);
    const float u = 0.5f * (pb[yp * W + px] - pb[ym * W + px]);
    const float v = -0.5f * (pb[py * W + xp] - pb[py * W + xm]);

    const float gx = (-1.f + 2.f * px / (float)(W - 1)) - u * (2.f / (float)W);
    const float gy = (-1.f + 2.f * py / (float)(H - 1)) - v * (2.f / (float)H);

    float ix = fminf(fmaxf((gx + 1.f) * 0.5f * (float)(W - 1), 0.f), (float)(W - 1));
    float iy = fminf(fmaxf((gy + 1.f) * 0.5f * (float)(H - 1), 0.f), (float)(H - 1));
    const float xf = floorf(ix), yf = floorf(iy);
    const float wx = ix - xf, wy = iy - yf;
    const int ix0 = (int)xf, iy0 = (int)yf;
    const int ix1 = min(ix0 + 1, W - 1), iy1 = min(iy0 + 1, H - 1);

    const int o00 = iy0 * W + ix0, o01 = iy0 * W + ix1;
    const int o10 = iy1 * W + ix0, o11 = iy1 * W + ix1;
    const float w00 = (1.f - wx) * (1.f - wy), w01 = wx * (1.f - wy);
    const float w10 = (1.f - wx) * wy, w11 = wx * wy;

    float* ob = out + (size_t)b * 128 * HWp + py * W + px;
    const float* zrb = zr + (size_t)b * 64 * HWp;
    const float* zib = zi + (size_t)b * 64 * HWp;
#pragma unroll 4
    for (int c = 0; c < 64; ++c) {
        const float* p = zrb + c * HWp;
        ob[c * HWp] = p[o00] * w00 + p[o01] * w01 + p[o10] * w10 + p[o11] * w11;
    }
#pragma unroll 4
    for (int c = 0; c < 64; ++c) {
        const float* p = zib + c * HWp;
        ob[(64 + c) * HWp] = p[o00] * w00 + p[o01] * w01 + p[o10] * w10 + p[o11] * w11;
    }
}

extern "C" void kernel_launch(void* const* d_in, const int* in_sizes, int n_in,
                              void* d_out, int out_size, void* d_ws, size_t ws_size,
                              hipStream_t stream) {
    const float* z_real = (const float*)d_in[0];
    const float* z_imag = (const float*)d_in[1];
    const float* dt     = (const float*)d_in[2];
    const float* w1     = (const float*)d_in[3];
    const float* b1     = (const float*)d_in[4];
    const float* w2     = (const float*)d_in[5];
    const float* b2     = (const float*)d_in[6];

    float* out = (float*)d_out;
    float* w1t = (float*)d_ws;            // 64*576 floats = 147 KB
    float* psi = w1t + 64 * 576;          // 4*256*256 floats = 1 MB
    float* act = out;                     // scratch: first 64*HW*4 floats of d_out,
                                          // consumed by k_conv2 before k_sample overwrites

    hipLaunchKernelGGL(k_wt, dim3(144), dim3(256), 0, stream, w1, w1t);
    hipLaunchKernelGGL(k_conv1, dim3(8, 32, 4), dim3(256), 0, stream, z_real, w1t, b1, act);
    hipLaunchKernelGGL(k_conv2, dim3(8, 32, 4), dim3(256), 0, stream, act, w2, b2, dt, psi);
    hipLaunchKernelGGL(k_sample, dim3(8, 32, 4), dim3(256), 0, stream, z_real, z_imag, psi, out);
}

// Round 2
// 268.024 us; speedup vs baseline: 1.4821x; 1.4821x over previous
//
#include <hip/hip_runtime.h>
#include <cmath>

namespace {
constexpr int H = 256, W = 256, C = 64;
constexpr int HWp = H * W;
}

typedef __attribute__((ext_vector_type(8))) __bf16 bf16x8;
typedef __attribute__((ext_vector_type(4))) float f32x4;
typedef __attribute__((ext_vector_type(4))) unsigned int u32x4;

__device__ __forceinline__ ushort f2bf(float f) {
    unsigned u = __builtin_bit_cast(unsigned, f);
    unsigned r = u + 0x7FFF + ((u >> 16) & 1);  // RNE
    return (ushort)(r >> 16);
}
__device__ __forceinline__ float bf2f(ushort s) {
    return __builtin_bit_cast(float, (unsigned)s << 16);
}

// K_wt: w1 [co][ci][3][3] fp32 -> w1tb [k9][co][ci] bf16 (ci contiguous)
__global__ void k_wt(const float* __restrict__ w1, ushort* __restrict__ w1tb) {
    int i = blockIdx.x * 256 + threadIdx.x;
    if (i >= 64 * 576) return;
    int co = i / 576, r = i - co * 576;
    int ci = r / 9, k9 = r - ci * 9;
    w1tb[(k9 * 64 + co) * 64 + ci] = f2bf(w1[i]);
}

// K_xt: z_real NCHW fp32 -> Xt NHWC bf16. Block: 64 px x 64 ci via LDS.
__global__ __launch_bounds__(256) void k_xt(const float* __restrict__ x,
                                            ushort* __restrict__ Xt) {
    __shared__ ushort tile[64][72];  // [px][ci], row 144 B (16-aligned)
    const int t = threadIdx.x;
    const int p0 = blockIdx.x * 64;
    const size_t base = (size_t)blockIdx.y * 64 * HWp;
#pragma unroll
    for (int r = 0; r < 16; ++r) {
        int idx = r * 256 + t;
        int ci = idx >> 6, px = idx & 63;
        tile[px][ci] = f2bf(x[base + (size_t)ci * HWp + p0 + px]);
    }
    __syncthreads();
    const int px = t >> 2, q = t & 3;
    uint4* dst = reinterpret_cast<uint4*>(Xt + ((size_t)blockIdx.y * HWp + p0 + px) * 64 + q * 16);
    const uint4* src = reinterpret_cast<const uint4*>(&tile[px][q * 16]);
    dst[0] = src[0];
    dst[1] = src[1];
}

// K1: conv1 via MFMA. Block = one row (256 px), 4 waves x (64 px, 64 co).
__global__ __launch_bounds__(256, 4) void k_conv1(
        const ushort* __restrict__ Xt,   // [B][HWp][64] bf16
        const ushort* __restrict__ w1tb, // [9][64co][64ci] bf16
        const float* __restrict__ b1,
        ushort* __restrict__ act) {      // [B][HWp][64] bf16
    const int wid = threadIdx.x >> 6;
    const int lane = threadIdx.x & 63;
    const int y = blockIdx.x;
    const int b = blockIdx.y;
    const int lr = lane & 15;   // A: pixel-in-mtile | B: co-in-ntile | C: col
    const int lg = lane >> 4;   // k-chunk group

    const int x_base = wid * 64;
    f32x4 acc[4][4];
#pragma unroll
    for (int m = 0; m < 4; ++m)
#pragma unroll
        for (int n = 0; n < 4; ++n) acc[m][n] = (f32x4)0.f;

    const size_t row_base = ((size_t)b * H + y) * W;
    const ushort* Arow = Xt + (row_base + x_base + lr) * 64 + lg * 8;
    const ushort* Bb = w1tb + (lr * 64 + lg * 8);

    const u32x4 z4 = (u32x4)0;
    const bf16x8 zf = __builtin_bit_cast(bf16x8, z4);

    for (int dy = -1; dy <= 1; ++dy) {
        const int yy = y + dy;
        if ((unsigned)yy >= (unsigned)H) continue;  // zero-pad row (uniform)
        const ushort* Ar = Arow + (ptrdiff_t)dy * W * 64;
#pragma unroll
        for (int dx = -1; dx <= 1; ++dx) {
            const int k9 = (dy + 1) * 3 + (dx + 1);
            const ushort* Bk = Bb + k9 * 64 * 64;
#pragma unroll
            for (int ci0 = 0; ci0 < 64; ci0 += 32) {
                bf16x8 bf[4];
#pragma unroll
                for (int n = 0; n < 4; ++n)
                    bf[n] = *reinterpret_cast<const bf16x8*>(Bk + n * 16 * 64 + ci0);
#pragma unroll
                for (int m = 0; m < 4; ++m) {
                    const int gx = x_base + m * 16 + lr + dx;
                    bf16x8 af = ((unsigned)gx < (unsigned)W)
                        ? *reinterpret_cast<const bf16x8*>(Ar + (ptrdiff_t)(m * 16 + dx) * 64 + ci0)
                        : zf;
#pragma unroll
                    for (int n = 0; n < 4; ++n)
                        acc[m][n] = __builtin_amdgcn_mfma_f32_16x16x32_bf16(
                            af, bf[n], acc[m][n], 0, 0, 0);
                }
            }
        }
    }

    // Epilogue: bias + SiLU -> act NHWC bf16. C/D: col=lr, row=lg*4+reg.
#pragma unroll
    for (int m = 0; m < 4; ++m) {
        const int px = x_base + m * 16 + lg * 4;
        ushort* ap = act + (row_base + px) * 64;
#pragma unroll
        for (int n = 0; n < 4; ++n) {
            const int co = n * 16 + lr;
            const float bias = b1[co];
#pragma unroll
            for (int r = 0; r < 4; ++r) {
                float v = acc[m][n][r] + bias;
                v = v / (1.f + __expf(-v));
                ap[(size_t)r * 64 + co] = f2bf(v);
            }
        }
    }
}

// K2: conv2 (64->1) + *dt -> psi. One thread per pixel, NHWC bf16 input.
__global__ __launch_bounds__(256) void k_conv2(
        const ushort* __restrict__ act, const float* __restrict__ w2,
        const float* __restrict__ b2, const float* __restrict__ dtp,
        float* __restrict__ psi) {
    const int tx = threadIdx.x & 31, ty = threadIdx.x >> 5;
    const int px = blockIdx.x * 32 + tx;
    const int py = blockIdx.y * 8 + ty;
    const int b = blockIdx.z;

    float a0 = 0.f, a1 = 0.f, a2 = 0.f, a3 = 0.f;
#pragma unroll
    for (int dy = -1; dy <= 1; ++dy) {
        const int yy = py + dy;
        if ((unsigned)yy >= (unsigned)H) continue;
#pragma unroll
        for (int dx = -1; dx <= 1; ++dx) {
            const int xx = px + dx;
            const int k9 = (dy + 1) * 3 + (dx + 1);
            if ((unsigned)xx < (unsigned)W) {
                const uint4* ap = reinterpret_cast<const uint4*>(
                    act + (((size_t)b * H + yy) * W + xx) * 64);
                const float* wp = w2 + k9;
#pragma unroll
                for (int c8 = 0; c8 < 8; ++c8) {
                    const uint4 v = ap[c8];
                    const int cb = c8 * 8;
                    a0 = fmaf(__builtin_bit_cast(float, v.x << 16),        wp[(cb + 0) * 9], a0);
                    a1 = fmaf(__builtin_bit_cast(float, v.x & 0xffff0000u), wp[(cb + 1) * 9], a1);
                    a2 = fmaf(__builtin_bit_cast(float, v.y << 16),        wp[(cb + 2) * 9], a2);
                    a3 = fmaf(__builtin_bit_cast(float, v.y & 0xffff0000u), wp[(cb + 3) * 9], a3);
                    a0 = fmaf(__builtin_bit_cast(float, v.z << 16),        wp[(cb + 4) * 9], a0);
                    a1 = fmaf(__builtin_bit_cast(float, v.z & 0xffff0000u), wp[(cb + 5) * 9], a1);
                    a2 = fmaf(__builtin_bit_cast(float, v.w << 16),        wp[(cb + 6) * 9], a2);
                    a3 = fmaf(__builtin_bit_cast(float, v.w & 0xffff0000u), wp[(cb + 7) * 9], a3);
                }
            }
        }
    }
    psi[((size_t)b * H + py) * W + px] = ((a0 + a1) + (a2 + a3) + b2[0]) * dtp[0];
}

// K3: curl(psi) -> flow -> bilinear border-clamped sample of 128 channels.
__global__ __launch_bounds__(256) void k_sample(
        const float* __restrict__ zr, const float* __restrict__ zi,
        const float* __restrict__ psi, float* __restrict__ out) {
    const int tx = threadIdx.x & 31, ty = threadIdx.x >> 5;
    const int px = blockIdx.x * 32 + tx;
    const int py = blockIdx.y * 8 + ty;
    const int b = blockIdx.z;

    const float* pb = psi + b * HWp;
    const int yp = min(py + 1, H - 1), ym = max(py - 1, 0);
    const int xp = min(px + 1, W - 1), xm = max(px - 1, 0);
    const float u = 0.5f * (pb[yp * W + px] - pb[ym * W + px]);
    const float v = -0.5f * (pb[py * W + xp] - pb[py * W + xm]);

    const float gx = (-1.f + 2.f * px / (float)(W - 1)) - u * (2.f / (float)W);
    const float gy = (-1.f + 2.f * py / (float)(H - 1)) - v * (2.f / (float)H);

    float ix = fminf(fmaxf((gx + 1.f) * 0.5f * (float)(W - 1), 0.f), (float)(W - 1));
    float iy = fminf(fmaxf((gy + 1.f) * 0.5f * (float)(H - 1), 0.f), (float)(H - 1));
    const float xf = floorf(ix), yf = floorf(iy);
    const float wx = ix - xf, wy = iy - yf;
    const int ix0 = (int)xf, iy0 = (int)yf;
    const int ix1 = min(ix0 + 1, W - 1), iy1 = min(iy0 + 1, H - 1);

    const int o00 = iy0 * W + ix0, o01 = iy0 * W + ix1;
    const int o10 = iy1 * W + ix0, o11 = iy1 * W + ix1;
    const float w00 = (1.f - wx) * (1.f - wy), w01 = wx * (1.f - wy);
    const float w10 = (1.f - wx) * wy, w11 = wx * wy;

    float* ob = out + (size_t)b * 128 * HWp + py * W + px;
    const float* zrb = zr + (size_t)b * 64 * HWp;
    const float* zib = zi + (size_t)b * 64 * HWp;
#pragma unroll 4
    for (int c = 0; c < 64; ++c) {
        const float* p = zrb + c * HWp;
        ob[c * HWp] = p[o00] * w00 + p[o01] * w01 + p[o10] * w10 + p[o11] * w11;
    }
#pragma unroll 4
    for (int c = 0; c < 64; ++c) {
        const float* p = zib + c * HWp;
        ob[(64 + c) * HWp] = p[o00] * w00 + p[o01] * w01 + p[o10] * w10 + p[o11] * w11;
    }
}

extern "C" void kernel_launch(void* const* d_in, const int* in_sizes, int n_in,
                              void* d_out, int out_size, void* d_ws, size_t ws_size,
                              hipStream_t stream) {
    const float* z_real = (const float*)d_in[0];
    const float* z_imag = (const float*)d_in[1];
    const float* dt     = (const float*)d_in[2];
    const float* w1     = (const float*)d_in[3];
    const float* b1     = (const float*)d_in[4];
    const float* w2     = (const float*)d_in[5];
    const float* b2     = (const float*)d_in[6];

    float* out = (float*)d_out;
    // ws: w1tb bf16 (73728 B) + psi fp32 (1 MB)
    ushort* w1tb = (ushort*)d_ws;
    float* psi = (float*)((char*)d_ws + 64 * 576 * sizeof(ushort));
    // d_out doubles as scratch before k_sample overwrites it:
    //   Xt  = d_out[0 .. 33.5 MB)   NHWC bf16 input
    //   act = d_out[33.5 .. 67 MB)  NHWC bf16 activations
    ushort* Xt  = (ushort*)d_out;
    ushort* act = (ushort*)d_out + (size_t)4 * HWp * 64;

    hipLaunchKernelGGL(k_wt, dim3(144), dim3(256), 0, stream, w1, w1tb);
    hipLaunchKernelGGL(k_xt, dim3(HWp / 64, 4), dim3(256), 0, stream, z_real, Xt);
    hipLaunchKernelGGL(k_conv1, dim3(256, 4), dim3(256), 0, stream, Xt, w1tb, b1, act);
    hipLaunchKernelGGL(k_conv2, dim3(8, 32, 4), dim3(256), 0, stream, act, w2, b2, dt, psi);
    hipLaunchKernelGGL(k_sample, dim3(8, 32, 4), dim3(256), 0, stream, z_real, z_imag, psi, out);
}

// Round 3
// 257.453 us; speedup vs baseline: 1.5430x; 1.0411x over previous
//
#include <hip/hip_runtime.h>
#include <cmath>

namespace {
constexpr int H = 256, W = 256, C = 64;
constexpr int HWp = H * W;
}

typedef __attribute__((ext_vector_type(8))) __bf16 bf16x8;
typedef __attribute__((ext_vector_type(4))) float f32x4;
typedef __attribute__((ext_vector_type(4))) unsigned int u32x4;

__device__ __forceinline__ ushort f2bf(float f) {
    unsigned u = __builtin_bit_cast(unsigned, f);
    unsigned r = u + 0x7FFF + ((u >> 16) & 1);  // RNE
    return (ushort)(r >> 16);
}

// K_wt: w1 [co][ci][3][3] fp32 -> w1tb [k9][co][ci] bf16 (ci contiguous)
__global__ void k_wt(const float* __restrict__ w1, ushort* __restrict__ w1tb) {
    int i = blockIdx.x * 256 + threadIdx.x;
    if (i >= 64 * 576) return;
    int co = i / 576, r = i - co * 576;
    int ci = r / 9, k9 = r - ci * 9;
    w1tb[(k9 * 64 + co) * 64 + ci] = f2bf(w1[i]);
}

// K_xt: z_real NCHW fp32 -> Xt NHWC bf16. Block: 64 px x 64 ci via LDS.
__global__ __launch_bounds__(256) void k_xt(const float* __restrict__ x,
                                            ushort* __restrict__ Xt) {
    __shared__ ushort tile[64][72];
    const int t = threadIdx.x;
    const int p0 = blockIdx.x * 64;
    const size_t base = (size_t)blockIdx.y * 64 * HWp;
#pragma unroll
    for (int r = 0; r < 16; ++r) {
        int idx = r * 256 + t;
        int ci = idx >> 6, px = idx & 63;
        tile[px][ci] = f2bf(x[base + (size_t)ci * HWp + p0 + px]);
    }
    __syncthreads();
    const int px = t >> 2, q = t & 3;
    uint4* dst = reinterpret_cast<uint4*>(Xt + ((size_t)blockIdx.y * HWp + p0 + px) * 64 + q * 16);
    const uint4* src = reinterpret_cast<const uint4*>(&tile[px][q * 16]);
    dst[0] = src[0];
    dst[1] = src[1];
}

// K1: conv1 via MFMA. Block = one row (256 px), 4 waves x (64 px, 64 co).
__global__ __launch_bounds__(256, 4) void k_conv1(
        const ushort* __restrict__ Xt,   // [B][HWp][64] bf16
        const ushort* __restrict__ w1tb, // [9][64co][64ci] bf16
        const float* __restrict__ b1,
        ushort* __restrict__ act) {      // [B][HWp][64] bf16
    const int wid = threadIdx.x >> 6;
    const int lane = threadIdx.x & 63;
    const int y = blockIdx.x;
    const int b = blockIdx.y;
    const int lr = lane & 15;
    const int lg = lane >> 4;

    const int x_base = wid * 64;
    f32x4 acc[4][4];
#pragma unroll
    for (int m = 0; m < 4; ++m)
#pragma unroll
        for (int n = 0; n < 4; ++n) acc[m][n] = (f32x4)0.f;

    const size_t row_base = ((size_t)b * H + y) * W;
    const ushort* Arow = Xt + (row_base + x_base + lr) * 64 + lg * 8;
    const ushort* Bb = w1tb + (lr * 64 + lg * 8);

    const u32x4 z4 = (u32x4)0;
    const bf16x8 zf = __builtin_bit_cast(bf16x8, z4);

    for (int dy = -1; dy <= 1; ++dy) {
        const int yy = y + dy;
        if ((unsigned)yy >= (unsigned)H) continue;
        const ushort* Ar = Arow + (ptrdiff_t)dy * W * 64;
#pragma unroll
        for (int dx = -1; dx <= 1; ++dx) {
            const int k9 = (dy + 1) * 3 + (dx + 1);
            const ushort* Bk = Bb + k9 * 64 * 64;
#pragma unroll
            for (int ci0 = 0; ci0 < 64; ci0 += 32) {
                bf16x8 bf[4];
#pragma unroll
                for (int n = 0; n < 4; ++n)
                    bf[n] = *reinterpret_cast<const bf16x8*>(Bk + n * 16 * 64 + ci0);
#pragma unroll
                for (int m = 0; m < 4; ++m) {
                    const int gx = x_base + m * 16 + lr + dx;
                    bf16x8 af = ((unsigned)gx < (unsigned)W)
                        ? *reinterpret_cast<const bf16x8*>(Ar + (ptrdiff_t)(m * 16 + dx) * 64 + ci0)
                        : zf;
#pragma unroll
                    for (int n = 0; n < 4; ++n)
                        acc[m][n] = __builtin_amdgcn_mfma_f32_16x16x32_bf16(
                            af, bf[n], acc[m][n], 0, 0, 0);
                }
            }
        }
    }

#pragma unroll
    for (int m = 0; m < 4; ++m) {
        const int px = x_base + m * 16 + lg * 4;
        ushort* ap = act + (row_base + px) * 64;
#pragma unroll
        for (int n = 0; n < 4; ++n) {
            const int co = n * 16 + lr;
            const float bias = b1[co];
#pragma unroll
            for (int r = 0; r < 4; ++r) {
                float v = acc[m][n][r] + bias;
                v = v / (1.f + __expf(-v));
                ap[(size_t)r * 64 + co] = f2bf(v);
            }
        }
    }
}

// K2: conv2 (64->1) + *dt -> psi. One thread per pixel, NHWC bf16 input.
__global__ __launch_bounds__(256) void k_conv2(
        const ushort* __restrict__ act, const float* __restrict__ w2,
        const float* __restrict__ b2, const float* __restrict__ dtp,
        float* __restrict__ psi) {
    const int tx = threadIdx.x & 31, ty = threadIdx.x >> 5;
    const int px = blockIdx.x * 32 + tx;
    const int py = blockIdx.y * 8 + ty;
    const int b = blockIdx.z;

    float a0 = 0.f, a1 = 0.f, a2 = 0.f, a3 = 0.f;
#pragma unroll
    for (int dy = -1; dy <= 1; ++dy) {
        const int yy = py + dy;
        if ((unsigned)yy >= (unsigned)H) continue;
#pragma unroll
        for (int dx = -1; dx <= 1; ++dx) {
            const int xx = px + dx;
            const int k9 = (dy + 1) * 3 + (dx + 1);
            if ((unsigned)xx < (unsigned)W) {
                const uint4* ap = reinterpret_cast<const uint4*>(
                    act + (((size_t)b * H + yy) * W + xx) * 64);
                const float* wp = w2 + k9;
#pragma unroll
                for (int c8 = 0; c8 < 8; ++c8) {
                    const uint4 v = ap[c8];
                    const int cb = c8 * 8;
                    a0 = fmaf(__builtin_bit_cast(float, v.x << 16),        wp[(cb + 0) * 9], a0);
                    a1 = fmaf(__builtin_bit_cast(float, v.x & 0xffff0000u), wp[(cb + 1) * 9], a1);
                    a2 = fmaf(__builtin_bit_cast(float, v.y << 16),        wp[(cb + 2) * 9], a2);
                    a3 = fmaf(__builtin_bit_cast(float, v.y & 0xffff0000u), wp[(cb + 3) * 9], a3);
                    a0 = fmaf(__builtin_bit_cast(float, v.z << 16),        wp[(cb + 4) * 9], a0);
                    a1 = fmaf(__builtin_bit_cast(float, v.z & 0xffff0000u), wp[(cb + 5) * 9], a1);
                    a2 = fmaf(__builtin_bit_cast(float, v.w << 16),        wp[(cb + 6) * 9], a2);
                    a3 = fmaf(__builtin_bit_cast(float, v.w & 0xffff0000u), wp[(cb + 7) * 9], a3);
                }
            }
        }
    }
    psi[((size_t)b * H + py) * W + px] = ((a0 + a1) + (a2 + a3) + b2[0]) * dtp[0];
}

// K3: curl(psi) -> flow -> bilinear sample. Channel-split: blockIdx.z = b*8+cg,
// each block handles 16 of the 128 output channels (flow recomputed per group).
__global__ __launch_bounds__(256) void k_sample(
        const float* __restrict__ zr, const float* __restrict__ zi,
        const float* __restrict__ psi, float* __restrict__ out) {
    const int tx = threadIdx.x & 31, ty = threadIdx.x >> 5;
    const int px = blockIdx.x * 32 + tx;
    const int py = blockIdx.y * 8 + ty;
    const int b  = blockIdx.z >> 3;
    const int c0 = (blockIdx.z & 7) * 16;  // combined-channel base (0..112)

    const float* pb = psi + b * HWp;
    const int yp = min(py + 1, H - 1), ym = max(py - 1, 0);
    const int xp = min(px + 1, W - 1), xm = max(px - 1, 0);
    const float u = 0.5f * (pb[yp * W + px] - pb[ym * W + px]);
    const float v = -0.5f * (pb[py * W + xp] - pb[py * W + xm]);

    const float gx = (-1.f + 2.f * px / (float)(W - 1)) - u * (2.f / (float)W);
    const float gy = (-1.f + 2.f * py / (float)(H - 1)) - v * (2.f / (float)H);

    float ix = fminf(fmaxf((gx + 1.f) * 0.5f * (float)(W - 1), 0.f), (float)(W - 1));
    float iy = fminf(fmaxf((gy + 1.f) * 0.5f * (float)(H - 1), 0.f), (float)(H - 1));
    const float xf = floorf(ix), yf = floorf(iy);
    const float wx = ix - xf, wy = iy - yf;
    const int ix0 = (int)xf, iy0 = (int)yf;
    const int ix1 = min(ix0 + 1, W - 1), iy1 = min(iy0 + 1, H - 1);

    const int o00 = iy0 * W + ix0, o01 = iy0 * W + ix1;
    const int o10 = iy1 * W + ix0, o11 = iy1 * W + ix1;
    const float w00 = (1.f - wx) * (1.f - wy), w01 = wx * (1.f - wy);
    const float w10 = (1.f - wx) * wy, w11 = wx * wy;

    // source plane base for combined channel cc: zr for cc<64 else zi
    const float* src0 = (c0 < 64) ? (zr + (size_t)b * 64 * HWp + (size_t)c0 * HWp)
                                  : (zi + (size_t)b * 64 * HWp + (size_t)(c0 - 64) * HWp);
    float* ob = out + ((size_t)b * 128 + c0) * HWp + py * W + px;

#pragma unroll
    for (int c = 0; c < 16; ++c) {
        const float* p = src0 + (size_t)c * HWp;
        ob[(size_t)c * HWp] = p[o00] * w00 + p[o01] * w01 + p[o10] * w10 + p[o11] * w11;
    }
}

extern "C" void kernel_launch(void* const* d_in, const int* in_sizes, int n_in,
                              void* d_out, int out_size, void* d_ws, size_t ws_size,
                              hipStream_t stream) {
    const float* z_real = (const float*)d_in[0];
    const float* z_imag = (const float*)d_in[1];
    const float* dt     = (const float*)d_in[2];
    const float* w1     = (const float*)d_in[3];
    const float* b1     = (const float*)d_in[4];
    const float* w2     = (const float*)d_in[5];
    const float* b2     = (const float*)d_in[6];

    float* out = (float*)d_out;
    ushort* w1tb = (ushort*)d_ws;
    float* psi = (float*)((char*)d_ws + 64 * 576 * sizeof(ushort));
    ushort* Xt  = (ushort*)d_out;                       // scratch in d_out
    ushort* act = (ushort*)d_out + (size_t)4 * HWp * 64;

    hipLaunchKernelGGL(k_wt, dim3(144), dim3(256), 0, stream, w1, w1tb);
    hipLaunchKernelGGL(k_xt, dim3(HWp / 64, 4), dim3(256), 0, stream, z_real, Xt);
    hipLaunchKernelGGL(k_conv1, dim3(256, 4), dim3(256), 0, stream, Xt, w1tb, b1, act);
    hipLaunchKernelGGL(k_conv2, dim3(8, 32, 4), dim3(256), 0, stream, act, w2, b2, dt, psi);
    hipLaunchKernelGGL(k_sample, dim3(8, 32, 32), dim3(256), 0, stream, z_real, z_imag, psi, out);
}